// Round 1
// baseline (24948.953 us; speedup 1.0000x reference)
//
#include <hip/hip_runtime.h>

// VanillaMPNN on MI355X — fp32 VALU baseline (round 0).
// h, agg live in d_ws. Weights staged in LDS, broadcast-read (wave-uniform).
// One thread per edge / node; fully unrolled 48x48 dense layers keep
// x[48]/t[48] in VGPRs (dynamic indexing would spill to scratch).

#define NE 48  // embedding dim

template<bool RELU>
__device__ __forceinline__ void dense48(const float* __restrict__ x,
                                        const float* __restrict__ W,   // LDS [48][48] row-major (k,j)
                                        const float* __restrict__ B,   // LDS [48]
                                        float* __restrict__ out) {
#pragma unroll
    for (int j0 = 0; j0 < NE; j0 += 4) {
        float4 acc = *(const float4*)(B + j0);
#pragma unroll
        for (int k = 0; k < NE; ++k) {
            float4 w = *(const float4*)(W + k * NE + j0);
            acc.x = fmaf(x[k], w.x, acc.x);
            acc.y = fmaf(x[k], w.y, acc.y);
            acc.z = fmaf(x[k], w.z, acc.z);
            acc.w = fmaf(x[k], w.w, acc.w);
        }
        if (RELU) {
            acc.x = fmaxf(acc.x, 0.0f); acc.y = fmaxf(acc.y, 0.0f);
            acc.z = fmaxf(acc.z, 0.0f); acc.w = fmaxf(acc.w, 0.0f);
        }
        out[j0 + 0] = acc.x; out[j0 + 1] = acc.y;
        out[j0 + 2] = acc.z; out[j0 + 3] = acc.w;
    }
}

__global__ __launch_bounds__(256) void embed_kernel(const int* __restrict__ an,
                                                    const float* __restrict__ emb,
                                                    float* __restrict__ h, int n4) {
    int i = blockIdx.x * 256 + threadIdx.x;   // over N*12 float4s
    if (i >= n4) return;
    int n = i / 12, q = i - n * 12;
    ((float4*)h)[i] = ((const float4*)emb)[an[n] * 12 + q];
}

__global__ __launch_bounds__(256) void edge_kernel(const float* __restrict__ h,
                                                   const int* __restrict__ src,
                                                   const int* __restrict__ dst,
                                                   const float* __restrict__ w1,
                                                   const float* __restrict__ b1,
                                                   const float* __restrict__ w2,
                                                   const float* __restrict__ b2,
                                                   float* __restrict__ agg, int E) {
    __shared__ __align__(16) float sW1[NE * NE];
    __shared__ __align__(16) float sW2[NE * NE];
    __shared__ __align__(16) float sB1[NE];
    __shared__ __align__(16) float sB2[NE];
    for (int i = threadIdx.x; i < NE * NE; i += 256) { sW1[i] = w1[i]; sW2[i] = w2[i]; }
    if (threadIdx.x < NE) { sB1[threadIdx.x] = b1[threadIdx.x]; sB2[threadIdx.x] = b2[threadIdx.x]; }
    __syncthreads();

    int e = blockIdx.x * 256 + threadIdx.x;
    if (e >= E) return;
    int s = src[e], d = dst[e];

    float x[NE];
    const float4* hs = (const float4*)(h + (size_t)s * NE);
    const float4* hd = (const float4*)(h + (size_t)d * NE);
#pragma unroll
    for (int k = 0; k < 12; ++k) {
        float4 a = hs[k], b = hd[k];
        x[4 * k + 0] = a.x * b.x; x[4 * k + 1] = a.y * b.y;
        x[4 * k + 2] = a.z * b.z; x[4 * k + 3] = a.w * b.w;
    }
    float t[NE], m[NE];
    dense48<true >(x, sW1, sB1, t);
    dense48<false>(t, sW2, sB2, m);

    float* ap = agg + (size_t)d * NE;
#pragma unroll
    for (int j = 0; j < NE; ++j) atomicAdd(ap + j, m[j]);
}

__global__ __launch_bounds__(256) void node_kernel(float* __restrict__ h,
                                                   const float* __restrict__ agg,
                                                   const float* __restrict__ w1,
                                                   const float* __restrict__ b1,
                                                   const float* __restrict__ w2,
                                                   const float* __restrict__ b2,
                                                   int N) {
    __shared__ __align__(16) float sW1[NE * NE];
    __shared__ __align__(16) float sW2[NE * NE];
    __shared__ __align__(16) float sB1[NE];
    __shared__ __align__(16) float sB2[NE];
    for (int i = threadIdx.x; i < NE * NE; i += 256) { sW1[i] = w1[i]; sW2[i] = w2[i]; }
    if (threadIdx.x < NE) { sB1[threadIdx.x] = b1[threadIdx.x]; sB2[threadIdx.x] = b2[threadIdx.x]; }
    __syncthreads();

    int n = blockIdx.x * 256 + threadIdx.x;
    if (n >= N) return;

    float x[NE];
    const float4* ag = (const float4*)(agg + (size_t)n * NE);
#pragma unroll
    for (int k = 0; k < 12; ++k) {
        float4 a = ag[k];
        x[4 * k + 0] = a.x; x[4 * k + 1] = a.y; x[4 * k + 2] = a.z; x[4 * k + 3] = a.w;
    }
    float t[NE], u[NE];
    dense48<true >(x, sW1, sB1, t);
    dense48<false>(t, sW2, sB2, u);

    float4* hp = (float4*)(h + (size_t)n * NE);
#pragma unroll
    for (int k = 0; k < 12; ++k) {
        float4 v = hp[k];
        v.x += u[4 * k + 0]; v.y += u[4 * k + 1];
        v.z += u[4 * k + 2]; v.w += u[4 * k + 3];
        hp[k] = v;
    }
}

__global__ __launch_bounds__(256) void readout_kernel(const float* __restrict__ h,
                                                      const int* __restrict__ graph_id,
                                                      const float* __restrict__ w1,
                                                      const float* __restrict__ b1,
                                                      const float* __restrict__ w2,  // [48]
                                                      const float* __restrict__ b2,  // [1]
                                                      float* __restrict__ out, int N) {
    __shared__ __align__(16) float sW1[NE * NE];
    __shared__ __align__(16) float sB1[NE];
    __shared__ __align__(16) float sW2[NE];
    for (int i = threadIdx.x; i < NE * NE; i += 256) sW1[i] = w1[i];
    if (threadIdx.x < NE) { sB1[threadIdx.x] = b1[threadIdx.x]; sW2[threadIdx.x] = w2[threadIdx.x]; }
    __syncthreads();

    int n = blockIdx.x * 256 + threadIdx.x;
    if (n >= N) return;

    float x[NE];
    const float4* hp = (const float4*)(h + (size_t)n * NE);
#pragma unroll
    for (int k = 0; k < 12; ++k) {
        float4 a = hp[k];
        x[4 * k + 0] = a.x; x[4 * k + 1] = a.y; x[4 * k + 2] = a.z; x[4 * k + 3] = a.w;
    }
    float t[NE];
    dense48<true>(x, sW1, sB1, t);
    float y = b2[0];
#pragma unroll
    for (int j = 0; j < NE; ++j) y = fmaf(t[j], sW2[j], y);
    atomicAdd(out + graph_id[n], y);
}

extern "C" void kernel_launch(void* const* d_in, const int* in_sizes, int n_in,
                              void* d_out, int out_size, void* d_ws, size_t ws_size,
                              hipStream_t stream) {
    const int*   AtomicNum = (const int*)  d_in[0];
    const int*   Edge      = (const int*)  d_in[1];
    const int*   graph_id  = (const int*)  d_in[2];
    const float* emb       = (const float*)d_in[3];
    const float* msg_w1    = (const float*)d_in[4];
    const float* msg_b1    = (const float*)d_in[5];
    const float* msg_w2    = (const float*)d_in[6];
    const float* msg_b2    = (const float*)d_in[7];
    const float* upd_w1    = (const float*)d_in[8];
    const float* upd_b1    = (const float*)d_in[9];
    const float* upd_w2    = (const float*)d_in[10];
    const float* upd_b2    = (const float*)d_in[11];
    const float* ro_w1     = (const float*)d_in[12];
    const float* ro_b1     = (const float*)d_in[13];
    const float* ro_w2     = (const float*)d_in[14];
    const float* ro_b2     = (const float*)d_in[15];

    const int N = in_sizes[0];          // 100000
    const int E = in_sizes[1] / 2;      // 1600000; src = Edge[0:E], dst = Edge[E:2E]
    const int* src = Edge;
    const int* dst = Edge + E;

    float* h   = (float*)d_ws;                       // [N,48]
    float* agg = h + (size_t)N * NE;                 // [N,48]

    hipMemsetAsync(d_out, 0, (size_t)out_size * sizeof(float), stream);

    int n4 = N * 12;
    embed_kernel<<<(n4 + 255) / 256, 256, 0, stream>>>(AtomicNum, emb, h, n4);

    for (int l = 0; l < 6; ++l) {
        hipMemsetAsync(agg, 0, (size_t)N * NE * sizeof(float), stream);
        edge_kernel<<<(E + 255) / 256, 256, 0, stream>>>(
            h, src, dst,
            msg_w1 + (size_t)l * NE * NE, msg_b1 + (size_t)l * NE,
            msg_w2 + (size_t)l * NE * NE, msg_b2 + (size_t)l * NE,
            agg, E);
        node_kernel<<<(N + 255) / 256, 256, 0, stream>>>(
            h, agg,
            upd_w1 + (size_t)l * NE * NE, upd_b1 + (size_t)l * NE,
            upd_w2 + (size_t)l * NE * NE, upd_b2 + (size_t)l * NE,
            N);
    }

    readout_kernel<<<(N + 255) / 256, 256, 0, stream>>>(
        h, graph_id, ro_w1, ro_b1, ro_w2, ro_b2, (float*)d_out, N);
}

// Round 2
// 4007.238 us; speedup vs baseline: 6.2260x; 6.2260x over previous
//
#include <hip/hip_runtime.h>

// VanillaMPNN on MI355X — round 1: atomic-free node-centric aggregation.
// CSR-by-dst built per launch (hist + scan + scatter, int atomics only).
// One fused kernel per layer: per-node edge loop -> message MLP (per-k fused,
// rolled loop for I$) -> register accumulate -> update MLP -> residual write
// to the other h buffer. No LDS (weights via wave-uniform global loads),
// no float atomics.

#define NE 48

// ---------------- embed ----------------
__global__ __launch_bounds__(256) void embed_kernel(const int* __restrict__ an,
                                                    const float* __restrict__ emb,
                                                    float* __restrict__ h, int n4) {
    int i = blockIdx.x * 256 + threadIdx.x;   // over N*12 float4s
    if (i >= n4) return;
    int n = i / 12, q = i - n * 12;
    ((float4*)h)[i] = ((const float4*)emb)[an[n] * 12 + q];
}

// ---------------- CSR build ----------------
__global__ __launch_bounds__(256) void hist_kernel(const int* __restrict__ dst,
                                                   int* __restrict__ cnt, int E) {
    int e = blockIdx.x * 256 + threadIdx.x;
    if (e < E) atomicAdd(&cnt[dst[e]], 1);
}

__global__ __launch_bounds__(1024) void scan_kernel(const int* __restrict__ cnt,
                                                    int* __restrict__ offs, int N) {
    __shared__ int swave[16];
    __shared__ int s_carry;
    const int tid = threadIdx.x;
    const int lane = tid & 63, wid = tid >> 6;
    if (tid == 0) s_carry = 0;
    __syncthreads();
    for (int base = 0; base < N; base += 1024) {
        int i = base + tid;
        int orig = (i < N) ? cnt[i] : 0;
        int v = orig;
#pragma unroll
        for (int off = 1; off < 64; off <<= 1) {
            int u = __shfl_up(v, off, 64);
            if (lane >= off) v += u;
        }
        if (lane == 63) swave[wid] = v;
        __syncthreads();
        if (wid == 0) {
            int w = (lane < 16) ? swave[lane] : 0;
#pragma unroll
            for (int off = 1; off < 16; off <<= 1) {
                int u = __shfl_up(w, off, 64);
                if (lane >= off) w += u;
            }
            if (lane < 16) swave[lane] = w;
        }
        __syncthreads();
        int prefix = (wid > 0) ? swave[wid - 1] : 0;
        int total = swave[15];
        int carry = s_carry;
        if (i < N) offs[i] = carry + prefix + v - orig;   // exclusive scan
        __syncthreads();
        if (tid == 0) s_carry = carry + total;
    }
}

__global__ __launch_bounds__(256) void scatter_kernel(const int* __restrict__ src,
                                                      const int* __restrict__ dst,
                                                      int* __restrict__ offs,   // becomes END offsets
                                                      int* __restrict__ colsrc, int E) {
    int e = blockIdx.x * 256 + threadIdx.x;
    if (e < E) {
        int p = atomicAdd(&offs[dst[e]], 1);
        colsrc[p] = src[e];
    }
}

__global__ __launch_bounds__(256) void transpose_kernel(const float* __restrict__ in,
                                                        float* __restrict__ out, int total) {
    int idx = blockIdx.x * 256 + threadIdx.x;
    if (idx >= total) return;
    int m = idx / (NE * NE), r = idx - m * NE * NE;
    int i = r / NE, j = r - i * NE;
    out[m * NE * NE + j * NE + i] = in[idx];
}

// ---------------- fused layer ----------------
__global__ __launch_bounds__(256, 2) void layer_kernel(
    const float* __restrict__ hin, float* __restrict__ hout,
    const int* __restrict__ colsrc, const int* __restrict__ ends,
    const int* __restrict__ cnt,
    const float* __restrict__ w1t, const float* __restrict__ b1,   // msg: W1 transposed, row k contiguous
    const float* __restrict__ w2,  const float* __restrict__ b2,   // msg: W2 row-major, row k contiguous
    const float* __restrict__ u1t, const float* __restrict__ ub1,  // upd: W1 transposed
    const float* __restrict__ u2,  const float* __restrict__ ub2,  // upd: W2 row-major
    int N)
{
    const int n = blockIdx.x * 256 + threadIdx.x;
    const bool nv = (n < N);
    const int nc = nv ? n : (N - 1);
    const int deg = nv ? cnt[nc] : 0;
    const int end = nv ? ends[nc] : 0;
    const int beg = end - deg;

    float hd[NE];
    const float4* hd4 = (const float4*)(hin + (size_t)nc * NE);
#pragma unroll
    for (int q = 0; q < 12; ++q) {
        float4 a = hd4[q];
        hd[4*q+0] = a.x; hd[4*q+1] = a.y; hd[4*q+2] = a.z; hd[4*q+3] = a.w;
    }

    float acc[NE];
#pragma unroll
    for (int j = 0; j < NE; ++j) acc[j] = 0.0f;

    // wave-uniform loop bound (keeps weight loads under uniform control)
    int wm = deg;
#pragma unroll
    for (int o = 1; o < 64; o <<= 1) {
        int t = __shfl_xor(wm, o, 64);
        wm = (t > wm) ? t : wm;
    }

    const float4* W1 = (const float4*)w1t;   // [48][12]
    const float4* W2 = (const float4*)w2;    // [48][12]

    for (int it = 0; it < wm; ++it) {
        int e = beg + it;
        bool v = (e < end);
        int s = colsrc[v ? e : 0];
        const float4* hs4 = (const float4*)(hin + (size_t)s * NE);
        float x[NE];
#pragma unroll
        for (int q = 0; q < 12; ++q) {
            float4 a = hs4[q];
            x[4*q+0] = a.x * hd[4*q+0];
            x[4*q+1] = a.y * hd[4*q+1];
            x[4*q+2] = a.z * hd[4*q+2];
            x[4*q+3] = a.w * hd[4*q+3];
        }
        // fused 2-layer message MLP: acc += relu(x@W1 + b1) @ W2  (b2 added later as deg*b2)
#pragma unroll 2
        for (int k = 0; k < NE; ++k) {
            float t = b1[k];
#pragma unroll
            for (int q = 0; q < 12; ++q) {
                float4 w = W1[k * 12 + q];
                t = fmaf(x[4*q+0], w.x, t);
                t = fmaf(x[4*q+1], w.y, t);
                t = fmaf(x[4*q+2], w.z, t);
                t = fmaf(x[4*q+3], w.w, t);
            }
            t = fmaxf(t, 0.0f);
            t = v ? t : 0.0f;      // mask lanes past their degree
#pragma unroll
            for (int q = 0; q < 12; ++q) {
                float4 w = W2[k * 12 + q];
                acc[4*q+0] = fmaf(t, w.x, acc[4*q+0]);
                acc[4*q+1] = fmaf(t, w.y, acc[4*q+1]);
                acc[4*q+2] = fmaf(t, w.z, acc[4*q+2]);
                acc[4*q+3] = fmaf(t, w.w, acc[4*q+3]);
            }
        }
    }

    // agg = acc + deg * b2
    float fdeg = (float)deg;
#pragma unroll
    for (int q = 0; q < 12; ++q) {
        float4 b = ((const float4*)b2)[q];
        acc[4*q+0] = fmaf(fdeg, b.x, acc[4*q+0]);
        acc[4*q+1] = fmaf(fdeg, b.y, acc[4*q+1]);
        acc[4*q+2] = fmaf(fdeg, b.z, acc[4*q+2]);
        acc[4*q+3] = fmaf(fdeg, b.w, acc[4*q+3]);
    }

    // update MLP + residual: out = hd + ub2 + sum_k relu(acc@U1[:,k] + ub1[k]) * U2[k,:]
    float outv[NE];
#pragma unroll
    for (int q = 0; q < 12; ++q) {
        float4 b = ((const float4*)ub2)[q];
        outv[4*q+0] = hd[4*q+0] + b.x;
        outv[4*q+1] = hd[4*q+1] + b.y;
        outv[4*q+2] = hd[4*q+2] + b.z;
        outv[4*q+3] = hd[4*q+3] + b.w;
    }
    const float4* U1 = (const float4*)u1t;
    const float4* U2 = (const float4*)u2;
#pragma unroll 2
    for (int k = 0; k < NE; ++k) {
        float t = ub1[k];
#pragma unroll
        for (int q = 0; q < 12; ++q) {
            float4 w = U1[k * 12 + q];
            t = fmaf(acc[4*q+0], w.x, t);
            t = fmaf(acc[4*q+1], w.y, t);
            t = fmaf(acc[4*q+2], w.z, t);
            t = fmaf(acc[4*q+3], w.w, t);
        }
        t = fmaxf(t, 0.0f);
#pragma unroll
        for (int q = 0; q < 12; ++q) {
            float4 w = U2[k * 12 + q];
            outv[4*q+0] = fmaf(t, w.x, outv[4*q+0]);
            outv[4*q+1] = fmaf(t, w.y, outv[4*q+1]);
            outv[4*q+2] = fmaf(t, w.z, outv[4*q+2]);
            outv[4*q+3] = fmaf(t, w.w, outv[4*q+3]);
        }
    }

    if (nv) {
        float4* ho = (float4*)(hout + (size_t)n * NE);
#pragma unroll
        for (int q = 0; q < 12; ++q)
            ho[q] = make_float4(outv[4*q+0], outv[4*q+1], outv[4*q+2], outv[4*q+3]);
    }
}

// ---------------- readout ----------------
__global__ __launch_bounds__(256) void readout_kernel(const float* __restrict__ h,
                                                      const int* __restrict__ gid,
                                                      const float* __restrict__ w1t,
                                                      const float* __restrict__ b1,
                                                      const float* __restrict__ w2,   // [48]
                                                      const float* __restrict__ b2,   // [1]
                                                      float* __restrict__ out, int N) {
    int n = blockIdx.x * 256 + threadIdx.x;
    if (n >= N) return;
    float x[NE];
    const float4* hp = (const float4*)(h + (size_t)n * NE);
#pragma unroll
    for (int q = 0; q < 12; ++q) {
        float4 a = hp[q];
        x[4*q+0] = a.x; x[4*q+1] = a.y; x[4*q+2] = a.z; x[4*q+3] = a.w;
    }
    const float4* W1 = (const float4*)w1t;
    float y = b2[0];
#pragma unroll 2
    for (int k = 0; k < NE; ++k) {
        float t = b1[k];
#pragma unroll
        for (int q = 0; q < 12; ++q) {
            float4 w = W1[k * 12 + q];
            t = fmaf(x[4*q+0], w.x, t);
            t = fmaf(x[4*q+1], w.y, t);
            t = fmaf(x[4*q+2], w.z, t);
            t = fmaf(x[4*q+3], w.w, t);
        }
        t = fmaxf(t, 0.0f);
        y = fmaf(t, w2[k], y);
    }
    atomicAdd(out + gid[n], y);
}

extern "C" void kernel_launch(void* const* d_in, const int* in_sizes, int n_in,
                              void* d_out, int out_size, void* d_ws, size_t ws_size,
                              hipStream_t stream) {
    const int*   AtomicNum = (const int*)  d_in[0];
    const int*   Edge      = (const int*)  d_in[1];
    const int*   graph_id  = (const int*)  d_in[2];
    const float* emb       = (const float*)d_in[3];
    const float* msg_w1    = (const float*)d_in[4];
    const float* msg_b1    = (const float*)d_in[5];
    const float* msg_w2    = (const float*)d_in[6];
    const float* msg_b2    = (const float*)d_in[7];
    const float* upd_w1    = (const float*)d_in[8];
    const float* upd_b1    = (const float*)d_in[9];
    const float* upd_w2    = (const float*)d_in[10];
    const float* upd_b2    = (const float*)d_in[11];
    const float* ro_w1     = (const float*)d_in[12];
    const float* ro_b1     = (const float*)d_in[13];
    const float* ro_w2     = (const float*)d_in[14];
    const float* ro_b2     = (const float*)d_in[15];

    const int N = in_sizes[0];          // 100000
    const int E = in_sizes[1] / 2;      // 1600000
    const int* src = Edge;
    const int* dst = Edge + E;

    // workspace layout
    float* h    = (float*)d_ws;                    // N*48
    float* h2   = h  + (size_t)N * NE;             // N*48
    float* w1t  = h2 + (size_t)N * NE;             // 6*2304
    float* u1t  = w1t + 6 * NE * NE;               // 6*2304
    float* rw1t = u1t + 6 * NE * NE;               // 2304
    int*   cnt    = (int*)(rw1t + NE * NE);        // N
    int*   offs   = cnt + N;                       // N (end-offsets after scatter)
    int*   colsrc = offs + N;                      // E

    hipMemsetAsync(d_out, 0, (size_t)out_size * sizeof(float), stream);
    hipMemsetAsync(cnt, 0, (size_t)N * sizeof(int), stream);

    int n4 = N * 12;
    embed_kernel<<<(n4 + 255) / 256, 256, 0, stream>>>(AtomicNum, emb, h, n4);

    hist_kernel<<<(E + 255) / 256, 256, 0, stream>>>(dst, cnt, E);
    scan_kernel<<<1, 1024, 0, stream>>>(cnt, offs, N);
    scatter_kernel<<<(E + 255) / 256, 256, 0, stream>>>(src, dst, offs, colsrc, E);

    transpose_kernel<<<(6 * NE * NE + 255) / 256, 256, 0, stream>>>(msg_w1, w1t, 6 * NE * NE);
    transpose_kernel<<<(6 * NE * NE + 255) / 256, 256, 0, stream>>>(upd_w1, u1t, 6 * NE * NE);
    transpose_kernel<<<(NE * NE + 255) / 256, 256, 0, stream>>>(ro_w1, rw1t, NE * NE);

    const float* hin = h;
    float* hout = h2;
    for (int l = 0; l < 6; ++l) {
        layer_kernel<<<(N + 255) / 256, 256, 0, stream>>>(
            hin, hout, colsrc, offs, cnt,
            w1t + (size_t)l * NE * NE, msg_b1 + (size_t)l * NE,
            msg_w2 + (size_t)l * NE * NE, msg_b2 + (size_t)l * NE,
            u1t + (size_t)l * NE * NE, upd_b1 + (size_t)l * NE,
            upd_w2 + (size_t)l * NE * NE, upd_b2 + (size_t)l * NE,
            N);
        const float* tmp = hin; hin = hout; hout = (float*)tmp;
    }

    // after 6 swaps the final features are back in h
    readout_kernel<<<(N + 255) / 256, 256, 0, stream>>>(
        hin, graph_id, rw1t, ro_b1, ro_w2, ro_b2, (float*)d_out, N);
}

// Round 3
// 3577.750 us; speedup vs baseline: 6.9734x; 1.1200x over previous
//
#include <hip/hip_runtime.h>

// VanillaMPNN on MI355X — round 2: edge-parallel message MLP (1 lane/edge,
// 25k waves) + in-wave segmented reduction by dst (edges CSR-sorted), tail
// lanes atomicAdd into hout (doubles as agg; zeroed per layer). Node kernel
// then does update MLP + residual in place. 4-partial dot chains for ILP.

#define NE 48

// ---------------- embed ----------------
__global__ __launch_bounds__(256) void embed_kernel(const int* __restrict__ an,
                                                    const float* __restrict__ emb,
                                                    float* __restrict__ h, int n4) {
    int i = blockIdx.x * 256 + threadIdx.x;   // over N*12 float4s
    if (i >= n4) return;
    int n = i / 12, q = i - n * 12;
    ((float4*)h)[i] = ((const float4*)emb)[an[n] * 12 + q];
}

// ---------------- CSR build ----------------
__global__ __launch_bounds__(256) void hist_kernel(const int* __restrict__ dst,
                                                   int* __restrict__ cnt, int E) {
    int e = blockIdx.x * 256 + threadIdx.x;
    if (e < E) atomicAdd(&cnt[dst[e]], 1);
}

__global__ __launch_bounds__(1024) void scan_kernel(const int* __restrict__ cnt,
                                                    int* __restrict__ offs, int N) {
    __shared__ int swave[16];
    __shared__ int s_carry;
    const int tid = threadIdx.x;
    const int lane = tid & 63, wid = tid >> 6;
    if (tid == 0) s_carry = 0;
    __syncthreads();
    for (int base = 0; base < N; base += 1024) {
        int i = base + tid;
        int orig = (i < N) ? cnt[i] : 0;
        int v = orig;
#pragma unroll
        for (int off = 1; off < 64; off <<= 1) {
            int u = __shfl_up(v, off, 64);
            if (lane >= off) v += u;
        }
        if (lane == 63) swave[wid] = v;
        __syncthreads();
        if (wid == 0) {
            int w = (lane < 16) ? swave[lane] : 0;
#pragma unroll
            for (int off = 1; off < 16; off <<= 1) {
                int u = __shfl_up(w, off, 64);
                if (lane >= off) w += u;
            }
            if (lane < 16) swave[lane] = w;
        }
        __syncthreads();
        int prefix = (wid > 0) ? swave[wid - 1] : 0;
        int total = swave[15];
        int carry = s_carry;
        if (i < N) offs[i] = carry + prefix + v - orig;   // exclusive scan
        __syncthreads();
        if (tid == 0) s_carry = carry + total;
    }
}

__global__ __launch_bounds__(256) void scatter_kernel(const int* __restrict__ src,
                                                      const int* __restrict__ dst,
                                                      int* __restrict__ offs,
                                                      int2* __restrict__ pair, int E) {
    int e = blockIdx.x * 256 + threadIdx.x;
    if (e < E) {
        int d = dst[e];
        int p = atomicAdd(&offs[d], 1);
        pair[p] = make_int2(src[e], d);   // sorted by d
    }
}

__global__ __launch_bounds__(256) void transpose_kernel(const float* __restrict__ in,
                                                        float* __restrict__ out, int total) {
    int idx = blockIdx.x * 256 + threadIdx.x;
    if (idx >= total) return;
    int m = idx / (NE * NE), r = idx - m * NE * NE;
    int i = r / NE, j = r - i * NE;
    out[m * NE * NE + j * NE + i] = in[idx];
}

// ---------------- edge message + segmented reduce ----------------
__global__ __launch_bounds__(256) void edge_kernel(
    const float* __restrict__ hin,
    const int2* __restrict__ pair,
    float* __restrict__ agg,                                        // == hout, pre-zeroed
    const float* __restrict__ w1t, const float* __restrict__ b1,    // W1 transposed [k][j... ] row k contiguous
    const float* __restrict__ w2,  const float* __restrict__ b2,    // W2 row-major, row k contiguous
    int E)
{
    const int p = blockIdx.x * 256 + threadIdx.x;
    const int lane = threadIdx.x & 63;
    const bool valid = (p < E);
    int2 sd = pair[valid ? p : (E - 1)];
    const int s = sd.x;
    const int d = valid ? sd.y : -1;    // -1: never merges, never emits

    const float4* hs4 = (const float4*)(hin + (size_t)s * NE);
    const float4* hd4 = (const float4*)(hin + (size_t)sd.y * NE);
    float x[NE];
#pragma unroll
    for (int q = 0; q < 12; ++q) {
        float4 a = hs4[q], b = hd4[q];
        x[4*q+0] = a.x * b.x; x[4*q+1] = a.y * b.y;
        x[4*q+2] = a.z * b.z; x[4*q+3] = a.w * b.w;
    }

    float m[NE];                        // message, seeded with b2 (per-edge bias)
#pragma unroll
    for (int q = 0; q < 12; ++q) {
        float4 b = ((const float4*)b2)[q];
        m[4*q+0] = b.x; m[4*q+1] = b.y; m[4*q+2] = b.z; m[4*q+3] = b.w;
    }

    const float4* W1 = (const float4*)w1t;   // [48][12]
    const float4* W2 = (const float4*)w2;    // [48][12]
#pragma unroll 3
    for (int k = 0; k < NE; ++k) {
        float t0 = b1[k], t1 = 0.0f, t2 = 0.0f, t3 = 0.0f;
#pragma unroll
        for (int q = 0; q < 12; ++q) {
            float4 w = W1[k * 12 + q];
            t0 = fmaf(x[4*q+0], w.x, t0);
            t1 = fmaf(x[4*q+1], w.y, t1);
            t2 = fmaf(x[4*q+2], w.z, t2);
            t3 = fmaf(x[4*q+3], w.w, t3);
        }
        float t = fmaxf((t0 + t1) + (t2 + t3), 0.0f);
#pragma unroll
        for (int q = 0; q < 12; ++q) {
            float4 w = W2[k * 12 + q];
            m[4*q+0] = fmaf(t, w.x, m[4*q+0]);
            m[4*q+1] = fmaf(t, w.y, m[4*q+1]);
            m[4*q+2] = fmaf(t, w.z, m[4*q+2]);
            m[4*q+3] = fmaf(t, w.w, m[4*q+3]);
        }
    }

    // in-wave inclusive segmented scan keyed on d (sorted within wave)
    int dn = __shfl_down(d, 1, 64);
    bool tail = (lane == 63) || (dn != d);
#pragma unroll
    for (int off = 1; off < 64; off <<= 1) {
        int dp = __shfl_up(d, off, 64);
        bool f = (lane >= off) && (dp == d);
        if (__any(f)) {
#pragma unroll
            for (int j = 0; j < NE; ++j) {
                float mu = __shfl_up(m[j], off, 64);
                m[j] += f ? mu : 0.0f;
            }
        }
    }

    if (valid && tail) {
        float* ap = agg + (size_t)d * NE;
#pragma unroll
        for (int j = 0; j < NE; ++j) atomicAdd(ap + j, m[j]);
    }
}

// ---------------- node update (in place on hout) ----------------
__global__ __launch_bounds__(256) void node_kernel(
    const float* __restrict__ hin,
    float* __restrict__ hout,                                       // holds agg on entry
    const float* __restrict__ u1t, const float* __restrict__ ub1,   // U1 transposed
    const float* __restrict__ u2,  const float* __restrict__ ub2,   // U2 row-major
    int N)
{
    int n = blockIdx.x * 256 + threadIdx.x;
    if (n >= N) return;

    float acc[NE];
    const float4* ag = (const float4*)(hout + (size_t)n * NE);
#pragma unroll
    for (int q = 0; q < 12; ++q) {
        float4 a = ag[q];
        acc[4*q+0] = a.x; acc[4*q+1] = a.y; acc[4*q+2] = a.z; acc[4*q+3] = a.w;
    }

    float outv[NE];
    const float4* hp = (const float4*)(hin + (size_t)n * NE);
#pragma unroll
    for (int q = 0; q < 12; ++q) {
        float4 a = hp[q];
        float4 b = ((const float4*)ub2)[q];
        outv[4*q+0] = a.x + b.x; outv[4*q+1] = a.y + b.y;
        outv[4*q+2] = a.z + b.z; outv[4*q+3] = a.w + b.w;
    }

    const float4* U1 = (const float4*)u1t;
    const float4* U2 = (const float4*)u2;
#pragma unroll 3
    for (int k = 0; k < NE; ++k) {
        float t0 = ub1[k], t1 = 0.0f, t2 = 0.0f, t3 = 0.0f;
#pragma unroll
        for (int q = 0; q < 12; ++q) {
            float4 w = U1[k * 12 + q];
            t0 = fmaf(acc[4*q+0], w.x, t0);
            t1 = fmaf(acc[4*q+1], w.y, t1);
            t2 = fmaf(acc[4*q+2], w.z, t2);
            t3 = fmaf(acc[4*q+3], w.w, t3);
        }
        float t = fmaxf((t0 + t1) + (t2 + t3), 0.0f);
#pragma unroll
        for (int q = 0; q < 12; ++q) {
            float4 w = U2[k * 12 + q];
            outv[4*q+0] = fmaf(t, w.x, outv[4*q+0]);
            outv[4*q+1] = fmaf(t, w.y, outv[4*q+1]);
            outv[4*q+2] = fmaf(t, w.z, outv[4*q+2]);
            outv[4*q+3] = fmaf(t, w.w, outv[4*q+3]);
        }
    }

    float4* ho = (float4*)(hout + (size_t)n * NE);
#pragma unroll
    for (int q = 0; q < 12; ++q)
        ho[q] = make_float4(outv[4*q+0], outv[4*q+1], outv[4*q+2], outv[4*q+3]);
}

// ---------------- readout ----------------
__global__ __launch_bounds__(256) void readout_kernel(const float* __restrict__ h,
                                                      const int* __restrict__ gid,
                                                      const float* __restrict__ w1t,
                                                      const float* __restrict__ b1,
                                                      const float* __restrict__ w2,   // [48]
                                                      const float* __restrict__ b2,   // [1]
                                                      float* __restrict__ out, int N) {
    int n = blockIdx.x * 256 + threadIdx.x;
    if (n >= N) return;
    float x[NE];
    const float4* hp = (const float4*)(h + (size_t)n * NE);
#pragma unroll
    for (int q = 0; q < 12; ++q) {
        float4 a = hp[q];
        x[4*q+0] = a.x; x[4*q+1] = a.y; x[4*q+2] = a.z; x[4*q+3] = a.w;
    }
    const float4* W1 = (const float4*)w1t;
    float y = b2[0];
#pragma unroll 3
    for (int k = 0; k < NE; ++k) {
        float t0 = b1[k], t1 = 0.0f, t2 = 0.0f, t3 = 0.0f;
#pragma unroll
        for (int q = 0; q < 12; ++q) {
            float4 w = W1[k * 12 + q];
            t0 = fmaf(x[4*q+0], w.x, t0);
            t1 = fmaf(x[4*q+1], w.y, t1);
            t2 = fmaf(x[4*q+2], w.z, t2);
            t3 = fmaf(x[4*q+3], w.w, t3);
        }
        float t = fmaxf((t0 + t1) + (t2 + t3), 0.0f);
        y = fmaf(t, w2[k], y);
    }
    atomicAdd(out + gid[n], y);
}

extern "C" void kernel_launch(void* const* d_in, const int* in_sizes, int n_in,
                              void* d_out, int out_size, void* d_ws, size_t ws_size,
                              hipStream_t stream) {
    const int*   AtomicNum = (const int*)  d_in[0];
    const int*   Edge      = (const int*)  d_in[1];
    const int*   graph_id  = (const int*)  d_in[2];
    const float* emb       = (const float*)d_in[3];
    const float* msg_w1    = (const float*)d_in[4];
    const float* msg_b1    = (const float*)d_in[5];
    const float* msg_w2    = (const float*)d_in[6];
    const float* msg_b2    = (const float*)d_in[7];
    const float* upd_w1    = (const float*)d_in[8];
    const float* upd_b1    = (const float*)d_in[9];
    const float* upd_w2    = (const float*)d_in[10];
    const float* upd_b2    = (const float*)d_in[11];
    const float* ro_w1     = (const float*)d_in[12];
    const float* ro_b1     = (const float*)d_in[13];
    const float* ro_w2     = (const float*)d_in[14];
    const float* ro_b2     = (const float*)d_in[15];

    const int N = in_sizes[0];          // 100000
    const int E = in_sizes[1] / 2;      // 1600000
    const int* src = Edge;
    const int* dst = Edge + E;

    // workspace layout (~52 MB)
    float* h    = (float*)d_ws;                    // N*48
    float* h2   = h  + (size_t)N * NE;             // N*48
    float* w1t  = h2 + (size_t)N * NE;             // 6*2304
    float* u1t  = w1t + 6 * NE * NE;               // 6*2304
    float* rw1t = u1t + 6 * NE * NE;               // 2304
    int*   cnt    = (int*)(rw1t + NE * NE);        // N
    int*   offs   = cnt + N;                       // N
    int2*  pair   = (int2*)(offs + N);             // E (src,dst) sorted by dst

    hipMemsetAsync(d_out, 0, (size_t)out_size * sizeof(float), stream);
    hipMemsetAsync(cnt, 0, (size_t)N * sizeof(int), stream);

    int n4 = N * 12;
    embed_kernel<<<(n4 + 255) / 256, 256, 0, stream>>>(AtomicNum, emb, h, n4);

    hist_kernel<<<(E + 255) / 256, 256, 0, stream>>>(dst, cnt, E);
    scan_kernel<<<1, 1024, 0, stream>>>(cnt, offs, N);
    scatter_kernel<<<(E + 255) / 256, 256, 0, stream>>>(src, dst, offs, pair, E);

    transpose_kernel<<<(6 * NE * NE + 255) / 256, 256, 0, stream>>>(msg_w1, w1t, 6 * NE * NE);
    transpose_kernel<<<(6 * NE * NE + 255) / 256, 256, 0, stream>>>(upd_w1, u1t, 6 * NE * NE);
    transpose_kernel<<<(NE * NE + 255) / 256, 256, 0, stream>>>(ro_w1, rw1t, NE * NE);

    const float* hin = h;
    float* hout = h2;
    for (int l = 0; l < 6; ++l) {
        hipMemsetAsync(hout, 0, (size_t)N * NE * sizeof(float), stream);
        edge_kernel<<<(E + 255) / 256, 256, 0, stream>>>(
            hin, pair, hout,
            w1t + (size_t)l * NE * NE, msg_b1 + (size_t)l * NE,
            msg_w2 + (size_t)l * NE * NE, msg_b2 + (size_t)l * NE,
            E);
        node_kernel<<<(N + 255) / 256, 256, 0, stream>>>(
            hin, hout,
            u1t + (size_t)l * NE * NE, upd_b1 + (size_t)l * NE,
            upd_w2 + (size_t)l * NE * NE, upd_b2 + (size_t)l * NE,
            N);
        const float* tmp = hin; hin = hout; hout = (float*)tmp;
    }

    readout_kernel<<<(N + 255) / 256, 256, 0, stream>>>(
        hin, graph_id, rw1t, ro_b1, ro_w2, ro_b2, (float*)d_out, N);
}